// Round 8
// baseline (330.308 us; speedup 1.0000x reference)
//
#include <hip/hip_runtime.h>
#include <hip/hip_bf16.h>

using bf16x8 = __attribute__((ext_vector_type(8))) __bf16;
using f32x4  = __attribute__((ext_vector_type(4))) float;

#define NB 8
#define SEQ 1024
#define HEADS 16
#define HD 64
#define EMB 1024

// exp domain: prefer native exp2 (one v_exp_f32), fold log2(e) into the Q prescale.
#if __has_builtin(__builtin_amdgcn_exp2f)
  #define EXPD(x) __builtin_amdgcn_exp2f(x)
  #define QSCALE  0.04508422f    /* (1/32) * log2(e) */
#else
  #define EXPD(x) __expf(x)
  #define QSCALE  0.03125f
#endif

__device__ __forceinline__ int cvtpk_bf16(float lo, float hi) {
    int r;
    asm("v_cvt_pk_bf16_f32 %0, %1, %2" : "=v"(r) : "v"(lo), "v"(hi));
    return r;
}

// e where mask-bit of this lane is set, else 0.0f. m is wave-uniform (SGPR pair).
__device__ __forceinline__ float sel0(float e, unsigned long long m) {
    float r;
    asm("v_cndmask_b32 %0, 0, %1, %2" : "=v"(r) : "v"(e), "s"(m));
    return r;
}

__device__ __forceinline__ void gld16(const __bf16* g, __bf16* l) {
    __builtin_amdgcn_global_load_lds((const __attribute__((address_space(1))) void*)g,
                                     (__attribute__((address_space(3))) void*)l, 16, 0, 0);
}

// ---------------- Kernel 0: mask permute (y<NB) + Wo f32->bf16 (y==NB) ----------------
// mq word (n,qg,w,g,kc,kt*4+r): bit l = (mask[n][qg*128+g*64+w*16+(l&15)][kc*64+kt*16+(l>>4)*4+r] != 0)
__global__ __launch_bounds__(256) void mask_perm(const int* __restrict__ mask,
                                                 unsigned long long* __restrict__ mq,
                                                 const float* __restrict__ Wo,
                                                 __bf16* __restrict__ Wob)
{
    __shared__ __align__(16) int Ms[128 * 68];
    const int t = threadIdx.x;
    if (blockIdx.y == NB) {
        // Wo conversion: 128 blocks x 256 thr x 32 elems = 1M elems, fully coalesced
        const size_t base = (size_t)blockIdx.x * 8192;
        #pragma unroll
        for (int jj = 0; jj < 8; ++jj) {
            const size_t off = base + (size_t)jj * 1024 + (size_t)t * 4;
            float4 f = *(const float4*)&Wo[off];
            union { __bf16 b[4]; uint2 u; } tmp;
            tmp.b[0] = (__bf16)f.x; tmp.b[1] = (__bf16)f.y;
            tmp.b[2] = (__bf16)f.z; tmp.b[3] = (__bf16)f.w;
            *(uint2*)&Wob[off] = tmp.u;
        }
        return;
    }
    const int w = t >> 6, lane = t & 63, quad = lane >> 4, lq = lane & 15;
    const int n = blockIdx.y;
    const int qg = blockIdx.x >> 4, kc = blockIdx.x & 15;
    const int* src = mask + ((size_t)n * SEQ + qg * 128) * SEQ + kc * 64;
    // 128 rows x 64 ints, 16 uint4 per row, 2048 chunks over 256 threads
    #pragma unroll
    for (int i = 0; i < 8; ++i) {
        const int c = t + i * 256, row = c >> 4, seg = c & 15;
        uint4 v = *(const uint4*)&src[(size_t)row * SEQ + seg * 4];
        *(uint4*)&Ms[row * 68 + seg * 4] = v;
    }
    __syncthreads();
    #pragma unroll
    for (int g = 0; g < 2; ++g) {
        const int row = (g * 64 + w * 16 + lq) * 68 + quad * 4;
        unsigned long long* dst = mq + ((size_t)(((n * 8 + qg) * 4 + w) * 2 + g) * 16 + kc) * 16;
        #pragma unroll
        for (int kt = 0; kt < 4; ++kt)
            #pragma unroll
            for (int r = 0; r < 4; ++r) {
                unsigned long long b = __ballot(Ms[row + kt * 16 + r] != 0);
                if (lane == 0) dst[kt * 4 + r] = b;
            }
    }
}

// ---------------- Kernel 1: per-head projection, MFMA (v1, proven) ----------------
// z=0: Q out (N,H,SEQ,64), pre-scaled by QSCALE.  z=1: K out.  z=2: V out transposed (N,H,64,SEQ).
__global__ __launch_bounds__(256, 4) void proj_mfma(
    const float* __restrict__ q_in, const float* __restrict__ k_in, const float* __restrict__ v_in,
    const float* __restrict__ Wq, const float* __restrict__ Wk, const float* __restrict__ Wv,
    __bf16* __restrict__ qp, __bf16* __restrict__ kp, __bf16* __restrict__ vpt)
{
    const int z = blockIdx.z;
    const float* X  = (z == 0) ? q_in : (z == 1) ? k_in : v_in;
    const float* Wf = (z == 0) ? Wq   : (z == 1) ? Wk   : Wv;

    __shared__ __align__(16) __bf16 Wb[64 * 72];  // Wb[e][d]
    __shared__ __align__(16) __bf16 Xb[64 * 72];  // Xb[l][d]; reused as output tile
    const int t = threadIdx.x;
    const int nh = blockIdx.y, n = nh >> 4, h = nh & 15;
    const int l0 = blockIdx.x * 64;
    for (int i = t; i < 4096; i += 256)
        Wb[(i >> 6) * 72 + (i & 63)] = (__bf16)Wf[i];
    {
        const int row = t >> 2, seg = (t & 3) * 16;
        const float* src = X + ((size_t)(n * SEQ + l0 + row)) * EMB + h * 64 + seg;
        union { __bf16 b[16]; uint4 u[2]; } tmp;
        #pragma unroll
        for (int jj = 0; jj < 4; ++jj) {
            float4 f = ((const float4*)src)[jj];
            tmp.b[jj*4+0] = (__bf16)f.x; tmp.b[jj*4+1] = (__bf16)f.y;
            tmp.b[jj*4+2] = (__bf16)f.z; tmp.b[jj*4+3] = (__bf16)f.w;
        }
        *(uint4*)&Xb[row * 72 + seg]     = tmp.u[0];
        *(uint4*)&Xb[row * 72 + seg + 8] = tmp.u[1];
    }
    __syncthreads();
    const int w = t >> 6, lane = t & 63, quad = lane >> 4, lr = lane & 15;
    bf16x8 af[2];
    #pragma unroll
    for (int ks = 0; ks < 2; ++ks)
        af[ks] = *(const bf16x8*)&Xb[(w * 16 + lr) * 72 + ks * 32 + quad * 8];
    const f32x4 zero4 = {0.f, 0.f, 0.f, 0.f};
    f32x4 acc[4];
    #pragma unroll
    for (int et = 0; et < 4; ++et) {
        acc[et] = zero4;
        #pragma unroll
        for (int ks = 0; ks < 2; ++ks) {
            bf16x8 bfrag = *(const bf16x8*)&Wb[(et * 16 + lr) * 72 + ks * 32 + quad * 8];
            acc[et] = __builtin_amdgcn_mfma_f32_16x16x32_bf16(af[ks], bfrag, acc[et], 0, 0, 0);
        }
    }
    if (z == 0) {
        #pragma unroll
        for (int et = 0; et < 4; ++et) acc[et] *= QSCALE;
    }
    __syncthreads();   // all waves past their Xb fragment reads (acc dependency)
    if (z < 2) {
        // tile[l][e] then coalesced row store
        #pragma unroll
        for (int et = 0; et < 4; ++et)
            #pragma unroll
            for (int rr = 0; rr < 4; ++rr)
                Xb[(w * 16 + quad * 4 + rr) * 72 + et * 16 + lr] = (__bf16)acc[et][rr];
        __syncthreads();
        const int row = t >> 2, seg = (t & 3) * 16;
        uint4 a = *(uint4*)&Xb[row * 72 + seg];
        uint4 b = *(uint4*)&Xb[row * 72 + seg + 8];
        __bf16* outp = (z == 0) ? qp : kp;
        __bf16* dst = outp + (size_t)nh * 65536 + (size_t)(l0 + row) * 64 + seg;
        *(uint4*)&dst[0] = a;
        *(uint4*)&dst[8] = b;
    } else {
        // tile[e][l] then coalesced row store into (N,H,64,SEQ)
        #pragma unroll
        for (int et = 0; et < 4; ++et)
            #pragma unroll
            for (int rr = 0; rr < 4; ++rr)
                Xb[(et * 16 + lr) * 72 + w * 16 + quad * 4 + rr] = (__bf16)acc[et][rr];
        __syncthreads();
        const int e = t >> 2, seg = (t & 3) * 16;
        uint4 a = *(uint4*)&Xb[e * 72 + seg];
        uint4 b = *(uint4*)&Xb[e * 72 + seg + 8];
        __bf16* dst = vpt + (size_t)nh * 65536 + (size_t)e * SEQ + l0 + seg;
        *(uint4*)&dst[0] = a;
        *(uint4*)&dst[8] = b;
    }
}

// ---------------- Kernel 2: MFMA flash attention, transposed-S, no-max softmax ----------------
// v8: NO LDS, NO BARRIERS. K/V fragments are read straight from global (L2/L1-resident:
// per-head working set 256 KB, XCD-pinned via stride-128 block swizzle; every wave read the
// whole tile anyway, so LDS staging was pure overhead + lockstep). All data-path math (QK,
// mask words, softmax, permlane redistribution, ones-MFMA l, output) byte-identical to v7.
__global__ __launch_bounds__(256, 3) void attn_mfma(
    const __bf16* __restrict__ qp, const __bf16* __restrict__ kp, const __bf16* __restrict__ vpt,
    const unsigned long long* __restrict__ mq, __bf16* __restrict__ attn_out)
{
    const int t = threadIdx.x, w = t >> 6, lane = t & 63, quad = lane >> 4, lr = lane & 15;
    const int bid = blockIdx.x;
    const int nh = bid & 127, qg = bid >> 7;       // same head -> same XCD (stride-128 blocks)
    const int n = nh >> 4, h = nh & 15;
    const int q0 = qg * 128;
    const __bf16* Q  = qp  + (size_t)nh * 65536;
    const __bf16* K  = kp  + (size_t)nh * 65536;
    const __bf16* VT = vpt + (size_t)nh * 65536;

    // wave-uniform base for the pre-permuted mask words (shared across heads)
    const int wu = __builtin_amdgcn_readfirstlane(w);
    const unsigned long long* mq_w = mq + (size_t)((n * 8 + qg) * 4 + wu) * 512;

    int qrow[2];
    bf16x8 qf[2][2];
    #pragma unroll
    for (int g = 0; g < 2; ++g) {
        qrow[g] = q0 + g * 64 + w * 16 + lr;
        qf[g][0] = *(const bf16x8*)&Q[(size_t)qrow[g] * 64 + quad * 8];
        qf[g][1] = *(const bf16x8*)&Q[(size_t)qrow[g] * 64 + 32 + quad * 8];
    }

    // all-ones A fragment: Lacc[g] = ones(16x32) @ P^T accumulates column sums of P^T = l per q.
    bf16x8 onesf;
    #pragma unroll
    for (int i = 0; i < 8; ++i) onesf[i] = (__bf16)1.0f;

    const f32x4 zero4 = {0.f, 0.f, 0.f, 0.f};
    f32x4 O[2][4];
    f32x4 Lacc[2];
    #pragma unroll
    for (int g = 0; g < 2; ++g) {
        Lacc[g] = zero4;
        #pragma unroll
        for (int mt = 0; mt < 4; ++mt) O[g][mt] = zero4;
    }

    for (int kc = 0; kc < 16; ++kc) {
        const __bf16* Kb = K  + (size_t)kc * 4096;       // K[key][d], 64x64
        const __bf16* Vb = VT + (size_t)kc * 64;         // V^T[d][key], row stride SEQ

        // S^T = K @ Q^T : col = q (lr), row = key = kt*16 + quad*4 + r.  kf shared across groups.
        f32x4 S[2][4];
        __builtin_amdgcn_s_setprio(1);
        #pragma unroll
        for (int kt = 0; kt < 4; ++kt) {
            bf16x8 kf0 = *(const bf16x8*)&Kb[(kt * 16 + lr) * 64 + quad * 8];
            bf16x8 kf1 = *(const bf16x8*)&Kb[(kt * 16 + lr) * 64 + 32 + quad * 8];
            S[0][kt] = __builtin_amdgcn_mfma_f32_16x16x32_bf16(kf0, qf[0][0], zero4, 0, 0, 0);
            S[1][kt] = __builtin_amdgcn_mfma_f32_16x16x32_bf16(kf0, qf[1][0], zero4, 0, 0, 0);
            S[0][kt] = __builtin_amdgcn_mfma_f32_16x16x32_bf16(kf1, qf[0][1], S[0][kt], 0, 0, 0);
            S[1][kt] = __builtin_amdgcn_mfma_f32_16x16x32_bf16(kf1, qf[1][1], S[1][kt], 0, 0, 0);
        }
        __builtin_amdgcn_s_setprio(0);

        // exp (unconditional, |S|<~3) -> one v_cndmask with SGPR lane-mask -> P^T B-fragments.
        bf16x8 pf[2][2];
        #pragma unroll
        for (int g = 0; g < 2; ++g) {
            const unsigned long long* Mg = mq_w + g * 256 + kc * 16;
            float ev[16];
            #pragma unroll
            for (int kt = 0; kt < 4; ++kt)
                #pragma unroll
                for (int r = 0; r < 4; ++r)
                    ev[kt * 4 + r] = sel0(EXPD(S[g][kt][r]), Mg[kt * 4 + r]);
            // lane(quad,lr) holds P^T keys 16kt+4quad+{0..3}; B-frag needs keys 32ks+8quad+{0..7}.
            #pragma unroll
            for (int ks = 0; ks < 2; ++ks) {
                const int ka = (2 * ks) * 4, kb2 = (2 * ks + 1) * 4;
                int d0 = cvtpk_bf16(ev[ka + 0], ev[ka + 1]);
                int d1 = cvtpk_bf16(ev[ka + 2], ev[ka + 3]);
                int d2 = cvtpk_bf16(ev[kb2 + 0], ev[kb2 + 1]);
                int d3 = cvtpk_bf16(ev[kb2 + 2], ev[kb2 + 3]);
                asm("v_permlane32_swap_b32 %0, %1" : "+v"(d0), "+v"(d2));
                asm("v_permlane16_swap_b32 %0, %1" : "+v"(d0), "+v"(d2));
                asm("v_permlane32_swap_b32 %0, %1" : "+v"(d1), "+v"(d3));
                asm("v_permlane16_swap_b32 %0, %1" : "+v"(d1), "+v"(d3));
                union { int di[4]; bf16x8 v; } pb;
                pb.di[0] = d0; pb.di[1] = d1; pb.di[2] = d2; pb.di[3] = d3;
                pf[g][ks] = pb.v;
            }
        }

        // O^T += V^T @ P^T ; V-frags shared across the two q-groups; l via ones-MFMA.
        __builtin_amdgcn_s_setprio(1);
        #pragma unroll
        for (int ks = 0; ks < 2; ++ks) {
            Lacc[0] = __builtin_amdgcn_mfma_f32_16x16x32_bf16(onesf, pf[0][ks], Lacc[0], 0, 0, 0);
            Lacc[1] = __builtin_amdgcn_mfma_f32_16x16x32_bf16(onesf, pf[1][ks], Lacc[1], 0, 0, 0);
            #pragma unroll
            for (int mt = 0; mt < 4; ++mt) {
                bf16x8 vf = *(const bf16x8*)&Vb[(size_t)(mt * 16 + lr) * SEQ + ks * 32 + quad * 8];
                O[0][mt] = __builtin_amdgcn_mfma_f32_16x16x32_bf16(vf, pf[0][ks], O[0][mt], 0, 0, 0);
                O[1][mt] = __builtin_amdgcn_mfma_f32_16x16x32_bf16(vf, pf[1][ks], O[1][mt], 0, 0, 0);
            }
        }
        __builtin_amdgcn_s_setprio(0);
    }
    #pragma unroll
    for (int g = 0; g < 2; ++g) {
        // every row of the ones-MFMA result equals the column sum: l for q=lr is in Lacc[g][*].
        const float linv = 1.0f / Lacc[g][0];
        #pragma unroll
        for (int mt = 0; mt < 4; ++mt) {
            union { __bf16 b[4]; uint2 u; } pk;
            #pragma unroll
            for (int r = 0; r < 4; ++r) pk.b[r] = (__bf16)(O[g][mt][r] * linv);
            *(uint2*)&attn_out[((size_t)n * SEQ + qrow[g]) * EMB + h * 64 + mt * 16 + quad * 4] = pk.u;
        }
    }
}

// ---------------- Kernel 3: out = A(8192x1024) @ Wob^T + bo, MFMA ----------------
// v2: 64x128 tile, BK=64, global_load_lds staging (XOR-swizzled source, linear dest,
//     swizzled fragment reads), double-buffered LDS (48 KB), one barrier per K-step.
__global__ __launch_bounds__(256, 3) void out_gemm_mfma(
    const __bf16* __restrict__ A, const __bf16* __restrict__ B,
    const float* __restrict__ bo, float* __restrict__ out)
{
    __shared__ __align__(16) __bf16 AB[2][(64 + 128) * 64];   // [buf][A 4096 | B 8192]
    const int t = threadIdx.x, w = t >> 6, lane = t & 63, quad = lane >> 4, lr = lane & 15;
    const int wr = (w >> 1) * 32, wc = (w & 1) * 64;
    const int r0 = blockIdx.y * 64, e0 = blockIdx.x * 128;

    // staging: chunk c covers row c>>3, 16B-slot c&7 (swizzled on the source side)
    const int srow = t >> 3, sj = t & 7;
    const int sswz = (sj ^ (srow & 7)) * 8;            // (srow+32k)&7 == srow&7

    auto issue = [&](int st) {
        __bf16* buf = (__bf16*)&AB[st & 1][0];
        const __bf16* as = A + (size_t)(r0 + srow) * EMB + st * 64 + sswz;
        const __bf16* bs = B + (size_t)(e0 + srow) * EMB + st * 64 + sswz;
        gld16(as,            buf + t * 8);
        gld16(as + 32 * EMB, buf + t * 8 + 2048);
        gld16(bs,            buf + 4096 + t * 8);
        gld16(bs + 32 * EMB, buf + 4096 + t * 8 + 2048);
        gld16(bs + 64 * EMB, buf + 4096 + t * 8 + 4096);
        gld16(bs + 96 * EMB, buf + 4096 + t * 8 + 6144);
    };

    const int s0 = (quad ^ (lr & 7)) * 8, s1 = s0 ^ 32;
    const f32x4 zero4 = {0.f, 0.f, 0.f, 0.f};
    f32x4 acc[2][4];
    #pragma unroll
    for (int mt = 0; mt < 2; ++mt)
        #pragma unroll
        for (int nt = 0; nt < 4; ++nt) acc[mt][nt] = zero4;

    issue(0);
    for (int st = 0; st < 16; ++st) {
        __syncthreads();                   // vmcnt drained before barrier: tile st in LDS
        if (st + 1 < 16) issue(st + 1);
        const __bf16* buf = (const __bf16*)&AB[st & 1][0];
        #pragma unroll
        for (int ks = 0; ks < 2; ++ks) {
            const int sv = ks ? s1 : s0;
            bf16x8 af[2], bf[4];
            #pragma unroll
            for (int mt = 0; mt < 2; ++mt)
                af[mt] = *(const bf16x8*)&buf[(wr + mt * 16 + lr) * 64 + sv];
            #pragma unroll
            for (int nt = 0; nt < 4; ++nt)
                bf[nt] = *(const bf16x8*)&buf[4096 + (wc + nt * 16 + lr) * 64 + sv];
            __builtin_amdgcn_s_setprio(1);
            #pragma unroll
            for (int mt = 0; mt < 2; ++mt)
                #pragma unroll
                for (int nt = 0; nt < 4; ++nt)
                    acc[mt][nt] = __builtin_amdgcn_mfma_f32_16x16x32_bf16(af[mt], bf[nt], acc[mt][nt], 0, 0, 0);
            __builtin_amdgcn_s_setprio(0);
        }
    }
    float bv[4];
    #pragma unroll
    for (int nt = 0; nt < 4; ++nt) bv[nt] = bo[e0 + wc + nt * 16 + lr];
    #pragma unroll
    for (int mt = 0; mt < 2; ++mt)
        #pragma unroll
        for (int nt = 0; nt < 4; ++nt)
            #pragma unroll
            for (int rr = 0; rr < 4; ++rr)
                out[(size_t)(r0 + wr + mt * 16 + quad * 4 + rr) * EMB + e0 + wc + nt * 16 + lr] =
                    acc[mt][nt][rr] + bv[nt];
}

extern "C" void kernel_launch(void* const* d_in, const int* in_sizes, int n_in,
                              void* d_out, int out_size, void* d_ws, size_t ws_size,
                              hipStream_t stream) {
    const float* values = (const float*)d_in[0];
    const float* keys   = (const float*)d_in[1];
    const float* query  = (const float*)d_in[2];
    const int*   mask   = (const int*)d_in[3];
    const float* Wv     = (const float*)d_in[4];
    const float* Wk     = (const float*)d_in[5];
    const float* Wq     = (const float*)d_in[6];
    const float* Wo     = (const float*)d_in[7];
    const float* bo     = (const float*)d_in[8];
    float* out = (float*)d_out;

    const size_t per = (size_t)NB * HEADS * SEQ * HD;  // 8,388,608 elems
    __bf16* qp   = (__bf16*)d_ws;
    __bf16* kp   = qp + per;
    __bf16* vpt  = kp + per;                         // V transposed (N,H,64,SEQ)
    __bf16* attn = vpt + per;                        // (N*SEQ, EMB)
    __bf16* Wob  = attn + (size_t)NB * SEQ * EMB;
    unsigned long long* maskq = (unsigned long long*)(Wob + (size_t)EMB * EMB);  // 1 MB

    mask_perm<<<dim3(128, NB + 1), 256, 0, stream>>>(mask, maskq, Wo, Wob);
    proj_mfma<<<dim3(16, 128, 3), 256, 0, stream>>>(query, keys, values, Wq, Wk, Wv, qp, kp, vpt);
    attn_mfma<<<1024, 256, 0, stream>>>(qp, kp, vpt, maskq, attn);
    out_gemm_mfma<<<dim3(EMB / 128, NB * SEQ / 64), 256, 0, stream>>>(attn, Wob, bo, out);
}

// Round 9
// 253.668 us; speedup vs baseline: 1.3021x; 1.3021x over previous
//
#include <hip/hip_runtime.h>
#include <hip/hip_bf16.h>

using bf16x8 = __attribute__((ext_vector_type(8))) __bf16;
using f32x4  = __attribute__((ext_vector_type(4))) float;

#define NB 8
#define SEQ 1024
#define HEADS 16
#define HD 64
#define EMB 1024

// exp domain: prefer native exp2 (one v_exp_f32), fold log2(e) into the Q prescale.
#if __has_builtin(__builtin_amdgcn_exp2f)
  #define EXPD(x) __builtin_amdgcn_exp2f(x)
  #define QSCALE  0.04508422f    /* (1/32) * log2(e) */
#else
  #define EXPD(x) __expf(x)
  #define QSCALE  0.03125f
#endif

__device__ __forceinline__ int cvtpk_bf16(float lo, float hi) {
    int r;
    asm("v_cvt_pk_bf16_f32 %0, %1, %2" : "=v"(r) : "v"(lo), "v"(hi));
    return r;
}

// e where mask-bit of this lane is set, else 0.0f. m is wave-uniform (SGPR pair).
__device__ __forceinline__ float sel0(float e, unsigned long long m) {
    float r;
    asm("v_cndmask_b32 %0, 0, %1, %2" : "=v"(r) : "v"(e), "s"(m));
    return r;
}

__device__ __forceinline__ void gld16(const __bf16* g, __bf16* l) {
    __builtin_amdgcn_global_load_lds((const __attribute__((address_space(1))) void*)g,
                                     (__attribute__((address_space(3))) void*)l, 16, 0, 0);
}

// ---------------- Kernel 0: mask permute (y<NB) + Wo f32->bf16 (y==NB) ----------------
// mq word (n,qg,w,g,kc,kt*4+r): bit l = (mask[n][qg*128+g*64+w*16+(l&15)][kc*64+kt*16+(l>>4)*4+r] != 0)
__global__ __launch_bounds__(256) void mask_perm(const int* __restrict__ mask,
                                                 unsigned long long* __restrict__ mq,
                                                 const float* __restrict__ Wo,
                                                 __bf16* __restrict__ Wob)
{
    __shared__ __align__(16) int Ms[128 * 68];
    const int t = threadIdx.x;
    if (blockIdx.y == NB) {
        // Wo conversion: 128 blocks x 256 thr x 32 elems = 1M elems, fully coalesced
        const size_t base = (size_t)blockIdx.x * 8192;
        #pragma unroll
        for (int jj = 0; jj < 8; ++jj) {
            const size_t off = base + (size_t)jj * 1024 + (size_t)t * 4;
            float4 f = *(const float4*)&Wo[off];
            union { __bf16 b[4]; uint2 u; } tmp;
            tmp.b[0] = (__bf16)f.x; tmp.b[1] = (__bf16)f.y;
            tmp.b[2] = (__bf16)f.z; tmp.b[3] = (__bf16)f.w;
            *(uint2*)&Wob[off] = tmp.u;
        }
        return;
    }
    const int w = t >> 6, lane = t & 63, quad = lane >> 4, lq = lane & 15;
    const int n = blockIdx.y;
    const int qg = blockIdx.x >> 4, kc = blockIdx.x & 15;
    const int* src = mask + ((size_t)n * SEQ + qg * 128) * SEQ + kc * 64;
    // 128 rows x 64 ints, 16 uint4 per row, 2048 chunks over 256 threads
    #pragma unroll
    for (int i = 0; i < 8; ++i) {
        const int c = t + i * 256, row = c >> 4, seg = c & 15;
        uint4 v = *(const uint4*)&src[(size_t)row * SEQ + seg * 4];
        *(uint4*)&Ms[row * 68 + seg * 4] = v;
    }
    __syncthreads();
    #pragma unroll
    for (int g = 0; g < 2; ++g) {
        const int row = (g * 64 + w * 16 + lq) * 68 + quad * 4;
        unsigned long long* dst = mq + ((size_t)(((n * 8 + qg) * 4 + w) * 2 + g) * 16 + kc) * 16;
        #pragma unroll
        for (int kt = 0; kt < 4; ++kt)
            #pragma unroll
            for (int r = 0; r < 4; ++r) {
                unsigned long long b = __ballot(Ms[row + kt * 16 + r] != 0);
                if (lane == 0) dst[kt * 4 + r] = b;
            }
    }
}

// ---------------- Kernel 1: per-head projection, MFMA (v1, proven) ----------------
// z=0: Q out (N,H,SEQ,64), pre-scaled by QSCALE.  z=1: K out.  z=2: V out transposed (N,H,64,SEQ).
__global__ __launch_bounds__(256, 4) void proj_mfma(
    const float* __restrict__ q_in, const float* __restrict__ k_in, const float* __restrict__ v_in,
    const float* __restrict__ Wq, const float* __restrict__ Wk, const float* __restrict__ Wv,
    __bf16* __restrict__ qp, __bf16* __restrict__ kp, __bf16* __restrict__ vpt)
{
    const int z = blockIdx.z;
    const float* X  = (z == 0) ? q_in : (z == 1) ? k_in : v_in;
    const float* Wf = (z == 0) ? Wq   : (z == 1) ? Wk   : Wv;

    __shared__ __align__(16) __bf16 Wb[64 * 72];  // Wb[e][d]
    __shared__ __align__(16) __bf16 Xb[64 * 72];  // Xb[l][d]; reused as output tile
    const int t = threadIdx.x;
    const int nh = blockIdx.y, n = nh >> 4, h = nh & 15;
    const int l0 = blockIdx.x * 64;
    for (int i = t; i < 4096; i += 256)
        Wb[(i >> 6) * 72 + (i & 63)] = (__bf16)Wf[i];
    {
        const int row = t >> 2, seg = (t & 3) * 16;
        const float* src = X + ((size_t)(n * SEQ + l0 + row)) * EMB + h * 64 + seg;
        union { __bf16 b[16]; uint4 u[2]; } tmp;
        #pragma unroll
        for (int jj = 0; jj < 4; ++jj) {
            float4 f = ((const float4*)src)[jj];
            tmp.b[jj*4+0] = (__bf16)f.x; tmp.b[jj*4+1] = (__bf16)f.y;
            tmp.b[jj*4+2] = (__bf16)f.z; tmp.b[jj*4+3] = (__bf16)f.w;
        }
        *(uint4*)&Xb[row * 72 + seg]     = tmp.u[0];
        *(uint4*)&Xb[row * 72 + seg + 8] = tmp.u[1];
    }
    __syncthreads();
    const int w = t >> 6, lane = t & 63, quad = lane >> 4, lr = lane & 15;
    bf16x8 af[2];
    #pragma unroll
    for (int ks = 0; ks < 2; ++ks)
        af[ks] = *(const bf16x8*)&Xb[(w * 16 + lr) * 72 + ks * 32 + quad * 8];
    const f32x4 zero4 = {0.f, 0.f, 0.f, 0.f};
    f32x4 acc[4];
    #pragma unroll
    for (int et = 0; et < 4; ++et) {
        acc[et] = zero4;
        #pragma unroll
        for (int ks = 0; ks < 2; ++ks) {
            bf16x8 bfrag = *(const bf16x8*)&Wb[(et * 16 + lr) * 72 + ks * 32 + quad * 8];
            acc[et] = __builtin_amdgcn_mfma_f32_16x16x32_bf16(af[ks], bfrag, acc[et], 0, 0, 0);
        }
    }
    if (z == 0) {
        #pragma unroll
        for (int et = 0; et < 4; ++et) acc[et] *= QSCALE;
    }
    __syncthreads();   // all waves past their Xb fragment reads (acc dependency)
    if (z < 2) {
        // tile[l][e] then coalesced row store
        #pragma unroll
        for (int et = 0; et < 4; ++et)
            #pragma unroll
            for (int rr = 0; rr < 4; ++rr)
                Xb[(w * 16 + quad * 4 + rr) * 72 + et * 16 + lr] = (__bf16)acc[et][rr];
        __syncthreads();
        const int row = t >> 2, seg = (t & 3) * 16;
        uint4 a = *(uint4*)&Xb[row * 72 + seg];
        uint4 b = *(uint4*)&Xb[row * 72 + seg + 8];
        __bf16* outp = (z == 0) ? qp : kp;
        __bf16* dst = outp + (size_t)nh * 65536 + (size_t)(l0 + row) * 64 + seg;
        *(uint4*)&dst[0] = a;
        *(uint4*)&dst[8] = b;
    } else {
        // tile[e][l] then coalesced row store into (N,H,64,SEQ)
        #pragma unroll
        for (int et = 0; et < 4; ++et)
            #pragma unroll
            for (int rr = 0; rr < 4; ++rr)
                Xb[(et * 16 + lr) * 72 + w * 16 + quad * 4 + rr] = (__bf16)acc[et][rr];
        __syncthreads();
        const int e = t >> 2, seg = (t & 3) * 16;
        uint4 a = *(uint4*)&Xb[e * 72 + seg];
        uint4 b = *(uint4*)&Xb[e * 72 + seg + 8];
        __bf16* dst = vpt + (size_t)nh * 65536 + (size_t)e * SEQ + l0 + seg;
        *(uint4*)&dst[0] = a;
        *(uint4*)&dst[8] = b;
    }
}

// ---------------- Kernel 2: MFMA flash attention, transposed-S, no-max softmax ----------------
// v7 (proven, 53.2 us): 128 q / block, 64-key chunks, grid 1024, 32 KB LDS, 4 blocks/CU,
// counted-vmcnt 2-phase staging: K and V issued separately; K(kc+1) stays in flight across both
// barriers of iter kc (never a vmcnt(0) drain in the steady state).
__global__ __launch_bounds__(256, 4) void attn_mfma(
    const __bf16* __restrict__ qp, const __bf16* __restrict__ kp, const __bf16* __restrict__ vpt,
    const unsigned long long* __restrict__ mq, __bf16* __restrict__ attn_out)
{
    __shared__ __align__(16) __bf16 KV[2][2][64 * 64];   // [buf][0=K,1=V^T][row*64+col], 32 KB
    const int t = threadIdx.x, w = t >> 6, lane = t & 63, quad = lane >> 4, lr = lane & 15;
    const int bid = blockIdx.x;
    const int nh = bid & 127, qg = bid >> 7;       // same head -> same XCD (stride-128 blocks)
    const int n = nh >> 4, h = nh & 15;
    const int q0 = qg * 128;
    const __bf16* Q  = qp  + (size_t)nh * 65536;
    const __bf16* K  = kp  + (size_t)nh * 65536;
    const __bf16* VT = vpt + (size_t)nh * 65536;

    // wave-uniform base for the pre-permuted mask words (shared across heads)
    const int wu = __builtin_amdgcn_readfirstlane(w);
    const unsigned long long* mq_w = mq + (size_t)((n * 8 + qg) * 4 + wu) * 512;

    int qrow[2];
    bf16x8 qf[2][2];
    #pragma unroll
    for (int g = 0; g < 2; ++g) {
        qrow[g] = q0 + g * 64 + w * 16 + lr;
        qf[g][0] = *(const bf16x8*)&Q[(size_t)qrow[g] * 64 + quad * 8];
        qf[g][1] = *(const bf16x8*)&Q[(size_t)qrow[g] * 64 + 32 + quad * 8];
    }

    // all-ones A fragment: Lacc[g] = ones(16x32) @ P^T accumulates column sums of P^T = l per q.
    bf16x8 onesf;
    #pragma unroll
    for (int i = 0; i < 8; ++i) onesf[i] = (__bf16)1.0f;

    // staging: thread t covers 16B chunks c=t and c=t+256 of each 8 KB tile.
    // source chunk index is XOR-swizzled by (row&7) so the *read* swizzle lands on linear data.
    const int srow = t >> 3, sc8 = t & 7;
    const int sswz = (sc8 ^ (srow & 7)) * 8;           // element offset of swizzled 16B chunk
    const int kofs = srow * 64 + sswz;                 // K[row][*]; second chunk = +32 rows
    const int vofs = srow * SEQ + sswz;                // V^T[d][*]; second chunk = +32 rows

    auto issueK = [&](int kc) {                        // 2 vmem instrs
        __bf16* kb = (__bf16*)&KV[kc & 1][0][0];
        const __bf16* ksrc = K + (size_t)kc * 4096 + kofs;
        gld16(ksrc,           kb + t * 8);
        gld16(ksrc + 32 * 64, kb + t * 8 + 2048);
    };
    auto issueV = [&](int kc) {                        // 2 vmem instrs
        __bf16* vb = (__bf16*)&KV[kc & 1][1][0];
        const __bf16* vsrc = VT + (size_t)kc * 64 + vofs;
        gld16(vsrc,            vb + t * 8);
        gld16(vsrc + 32 * SEQ, vb + t * 8 + 2048);
    };

    // per-lane swizzled fragment offsets: chunk j = 4*ks+quad lives at slot j^(lr&7)
    const int s0 = ((quad ^ (lr & 7))) * 8;            // ks=0
    const int s1 = s0 ^ 32;                            // ks=1 (chunk j^4 -> slot offset ^32 elems)

    const f32x4 zero4 = {0.f, 0.f, 0.f, 0.f};
    f32x4 O[2][4];
    f32x4 Lacc[2];
    #pragma unroll
    for (int g = 0; g < 2; ++g) {
        Lacc[g] = zero4;
        #pragma unroll
        for (int mt = 0; mt < 4; ++mt) O[g][mt] = zero4;
    }

    // prologue: 6 vmem in flight (K0, V0, K1)
    issueK(0); issueV(0); issueK(1);
    for (int kc = 0; kc < 16; ++kc) {
        // --- K phase: need K(kc) landed; V(kc) [+K(kc+1) if kc<15] stay in flight ---
        if (kc < 15) asm volatile("s_waitcnt vmcnt(4)" ::: "memory");
        else         asm volatile("s_waitcnt vmcnt(2)" ::: "memory");
        __builtin_amdgcn_s_barrier();
        const __bf16* Kb = (const __bf16*)&KV[kc & 1][0][0];
        const __bf16* Vb = (const __bf16*)&KV[kc & 1][1][0];

        // S^T = K @ Q^T : col = q (lr), row = key = kt*16 + quad*4 + r.  kf shared across groups.
        f32x4 S[2][4];
        __builtin_amdgcn_s_setprio(1);
        #pragma unroll
        for (int kt = 0; kt < 4; ++kt) {
            bf16x8 kf0 = *(const bf16x8*)&Kb[(kt * 16 + lr) * 64 + s0];
            bf16x8 kf1 = *(const bf16x8*)&Kb[(kt * 16 + lr) * 64 + s1];
            S[0][kt] = __builtin_amdgcn_mfma_f32_16x16x32_bf16(kf0, qf[0][0], zero4, 0, 0, 0);
            S[1][kt] = __builtin_amdgcn_mfma_f32_16x16x32_bf16(kf0, qf[1][0], zero4, 0, 0, 0);
            S[0][kt] = __builtin_amdgcn_mfma_f32_16x16x32_bf16(kf1, qf[0][1], S[0][kt], 0, 0, 0);
            S[1][kt] = __builtin_amdgcn_mfma_f32_16x16x32_bf16(kf1, qf[1][1], S[1][kt], 0, 0, 0);
        }
        __builtin_amdgcn_s_setprio(0);

        // --- V phase: need V(kc) landed; K(kc+1) stays in flight ---
        if (kc < 15) asm volatile("s_waitcnt vmcnt(2)" ::: "memory");
        else         asm volatile("s_waitcnt vmcnt(0)" ::: "memory");
        __builtin_amdgcn_s_barrier();
        if (kc + 1 < 16) issueV(kc + 1);   // safe: all waves past PV(kc-1) at this barrier

        // exp (unconditional, |S|<~3) -> one v_cndmask with SGPR lane-mask -> P^T B-fragments.
        bf16x8 pf[2][2];
        #pragma unroll
        for (int g = 0; g < 2; ++g) {
            const unsigned long long* Mg = mq_w + g * 256 + kc * 16;
            float ev[16];
            #pragma unroll
            for (int kt = 0; kt < 4; ++kt)
                #pragma unroll
                for (int r = 0; r < 4; ++r)
                    ev[kt * 4 + r] = sel0(EXPD(S[g][kt][r]), Mg[kt * 4 + r]);
            // lane(quad,lr) holds P^T keys 16kt+4quad+{0..3}; B-frag needs keys 32ks+8quad+{0..7}.
            #pragma unroll
            for (int ks = 0; ks < 2; ++ks) {
                const int ka = (2 * ks) * 4, kb2 = (2 * ks + 1) * 4;
                int d0 = cvtpk_bf16(ev[ka + 0], ev[ka + 1]);
                int d1 = cvtpk_bf16(ev[ka + 2], ev[ka + 3]);
                int d2 = cvtpk_bf16(ev[kb2 + 0], ev[kb2 + 1]);
                int d3 = cvtpk_bf16(ev[kb2 + 2], ev[kb2 + 3]);
                asm("v_permlane32_swap_b32 %0, %1" : "+v"(d0), "+v"(d2));
                asm("v_permlane16_swap_b32 %0, %1" : "+v"(d0), "+v"(d2));
                asm("v_permlane32_swap_b32 %0, %1" : "+v"(d1), "+v"(d3));
                asm("v_permlane16_swap_b32 %0, %1" : "+v"(d1), "+v"(d3));
                union { int di[4]; bf16x8 v; } pb;
                pb.di[0] = d0; pb.di[1] = d1; pb.di[2] = d2; pb.di[3] = d3;
                pf[g][ks] = pb.v;
            }
        }

        // O^T += V^T @ P^T ; V-frags shared across the two q-groups; l via ones-MFMA.
        __builtin_amdgcn_s_setprio(1);
        #pragma unroll
        for (int ks = 0; ks < 2; ++ks) {
            const int sv = ks ? s1 : s0;
            Lacc[0] = __builtin_amdgcn_mfma_f32_16x16x32_bf16(onesf, pf[0][ks], Lacc[0], 0, 0, 0);
            Lacc[1] = __builtin_amdgcn_mfma_f32_16x16x32_bf16(onesf, pf[1][ks], Lacc[1], 0, 0, 0);
            #pragma unroll
            for (int mt = 0; mt < 4; ++mt) {
                bf16x8 vf = *(const bf16x8*)&Vb[(mt * 16 + lr) * 64 + sv];
                O[0][mt] = __builtin_amdgcn_mfma_f32_16x16x32_bf16(vf, pf[0][ks], O[0][mt], 0, 0, 0);
                O[1][mt] = __builtin_amdgcn_mfma_f32_16x16x32_bf16(vf, pf[1][ks], O[1][mt], 0, 0, 0);
            }
        }
        __builtin_amdgcn_s_setprio(0);
        if (kc + 2 < 16) issueK(kc + 2);   // safe: all waves finished QK(kc) reads at barrierV
    }
    #pragma unroll
    for (int g = 0; g < 2; ++g) {
        // every row of the ones-MFMA result equals the column sum: l for q=lr is in Lacc[g][*].
        const float linv = 1.0f / Lacc[g][0];
        #pragma unroll
        for (int mt = 0; mt < 4; ++mt) {
            union { __bf16 b[4]; uint2 u; } pk;
            #pragma unroll
            for (int r = 0; r < 4; ++r) pk.b[r] = (__bf16)(O[g][mt][r] * linv);
            *(uint2*)&attn_out[((size_t)n * SEQ + qrow[g]) * EMB + h * 64 + mt * 16 + quad * 4] = pk.u;
        }
    }
}

// ---------------- Kernel 3: out = A(8192x1024) @ Wob^T + bo, MFMA ----------------
// v3 = v2 + XCD band swizzle: bijective block-id remap so XCD s owns a contiguous 16-tile
// band of A rows (2 MB) + all of Wob (2 MB) -> per-XCD working set = L2 size (4 MB).
// Pure index permutation of independent blocks: zero correctness risk.
__global__ __launch_bounds__(256, 3) void out_gemm_mfma(
    const __bf16* __restrict__ A, const __bf16* __restrict__ B,
    const float* __restrict__ bo, float* __restrict__ out)
{
    __shared__ __align__(16) __bf16 AB[2][(64 + 128) * 64];   // [buf][A 4096 | B 8192]
    const int t = threadIdx.x, w = t >> 6, lane = t & 63, quad = lane >> 4, lr = lane & 15;
    const int wr = (w >> 1) * 32, wc = (w & 1) * 64;
    // band swizzle: L = bx + 8*by (the dispatch order); XCD = L%8 gets by' in [16s,16s+16)
    const int L = blockIdx.x + 8 * blockIdx.y;
    const int s = L & 7, c = L >> 3;
    const int bx = c >> 4, by = (s << 4) | (c & 15);
    const int r0 = by * 64, e0 = bx * 128;

    // staging: chunk c covers row c>>3, 16B-slot c&7 (swizzled on the source side)
    const int srow = t >> 3, sj = t & 7;
    const int sswz = (sj ^ (srow & 7)) * 8;            // (srow+32k)&7 == srow&7

    auto issue = [&](int st) {
        __bf16* buf = (__bf16*)&AB[st & 1][0];
        const __bf16* as = A + (size_t)(r0 + srow) * EMB + st * 64 + sswz;
        const __bf16* bs = B + (size_t)(e0 + srow) * EMB + st * 64 + sswz;
        gld16(as,            buf + t * 8);
        gld16(as + 32 * EMB, buf + t * 8 + 2048);
        gld16(bs,            buf + 4096 + t * 8);
        gld16(bs + 32 * EMB, buf + 4096 + t * 8 + 2048);
        gld16(bs + 64 * EMB, buf + 4096 + t * 8 + 4096);
        gld16(bs + 96 * EMB, buf + 4096 + t * 8 + 6144);
    };

    const int s0 = (quad ^ (lr & 7)) * 8, s1 = s0 ^ 32;
    const f32x4 zero4 = {0.f, 0.f, 0.f, 0.f};
    f32x4 acc[2][4];
    #pragma unroll
    for (int mt = 0; mt < 2; ++mt)
        #pragma unroll
        for (int nt = 0; nt < 4; ++nt) acc[mt][nt] = zero4;

    issue(0);
    for (int st = 0; st < 16; ++st) {
        __syncthreads();                   // vmcnt drained before barrier: tile st in LDS
        if (st + 1 < 16) issue(st + 1);
        const __bf16* buf = (const __bf16*)&AB[st & 1][0];
        #pragma unroll
        for (int ks = 0; ks < 2; ++ks) {
            const int sv = ks ? s1 : s0;
            bf16x8 af[2], bf[4];
            #pragma unroll
            for (int mt = 0; mt < 2; ++mt)
                af[mt] = *(const bf16x8*)&buf[(wr + mt * 16 + lr) * 64 + sv];
            #pragma unroll
            for (int nt = 0; nt < 4; ++nt)
                bf[nt] = *(const bf16x8*)&buf[4096 + (wc + nt * 16 + lr) * 64 + sv];
            __builtin_amdgcn_s_setprio(1);
            #pragma unroll
            for (int mt = 0; mt < 2; ++mt)
                #pragma unroll
                for (int nt = 0; nt < 4; ++nt)
                    acc[mt][nt] = __builtin_amdgcn_mfma_f32_16x16x32_bf16(af[mt], bf[nt], acc[mt][nt], 0, 0, 0);
            __builtin_amdgcn_s_setprio(0);
        }
    }
    float bv[4];
    #pragma unroll
    for (int nt = 0; nt < 4; ++nt) bv[nt] = bo[e0 + wc + nt * 16 + lr];
    #pragma unroll
    for (int mt = 0; mt < 2; ++mt)
        #pragma unroll
        for (int nt = 0; nt < 4; ++nt)
            #pragma unroll
            for (int rr = 0; rr < 4; ++rr)
                out[(size_t)(r0 + wr + mt * 16 + quad * 4 + rr) * EMB + e0 + wc + nt * 16 + lr] =
                    acc[mt][nt][rr] + bv[nt];
}

extern "C" void kernel_launch(void* const* d_in, const int* in_sizes, int n_in,
                              void* d_out, int out_size, void* d_ws, size_t ws_size,
                              hipStream_t stream) {
    const float* values = (const float*)d_in[0];
    const float* keys   = (const float*)d_in[1];
    const float* query  = (const float*)d_in[2];
    const int*   mask   = (const int*)d_in[3];
    const float* Wv     = (const float*)d_in[4];
    const float* Wk     = (const float*)d_in[5];
    const float* Wq     = (const float*)d_in[6];
    const float* Wo     = (const float*)d_in[7];
    const float* bo     = (const float*)d_in[8];
    float* out = (float*)d_out;

    const size_t per = (size_t)NB * HEADS * SEQ * HD;  // 8,388,608 elems
    __bf16* qp   = (__bf16*)d_ws;
    __bf16* kp   = qp + per;
    __bf16* vpt  = kp + per;                         // V transposed (N,H,64,SEQ)
    __bf16* attn = vpt + per;                        // (N*SEQ, EMB)
    __bf16* Wob  = attn + (size_t)NB * SEQ * EMB;
    unsigned long long* maskq = (unsigned long long*)(Wob + (size_t)EMB * EMB);  // 1 MB

    mask_perm<<<dim3(128, NB + 1), 256, 0, stream>>>(mask, maskq, Wo, Wob);
    proj_mfma<<<dim3(16, 128, 3), 256, 0, stream>>>(query, keys, values, Wq, Wk, Wv, qp, kp, vpt);
    attn_mfma<<<1024, 256, 0, stream>>>(qp, kp, vpt, maskq, attn);
    out_gemm_mfma<<<dim3(EMB / 128, NB * SEQ / 64), 256, 0, stream>>>(attn, Wob, bo, out);
}

// Round 10
// 247.695 us; speedup vs baseline: 1.3335x; 1.0241x over previous
//
#include <hip/hip_runtime.h>
#include <hip/hip_bf16.h>

using bf16x8 = __attribute__((ext_vector_type(8))) __bf16;
using f32x4  = __attribute__((ext_vector_type(4))) float;

#define NB 8
#define SEQ 1024
#define HEADS 16
#define HD 64
#define EMB 1024

// exp domain: prefer native exp2 (one v_exp_f32), fold log2(e) into the Q prescale.
#if __has_builtin(__builtin_amdgcn_exp2f)
  #define EXPD(x) __builtin_amdgcn_exp2f(x)
  #define QSCALE  0.04508422f    /* (1/32) * log2(e) */
#else
  #define EXPD(x) __expf(x)
  #define QSCALE  0.03125f
#endif

__device__ __forceinline__ int cvtpk_bf16(float lo, float hi) {
    int r;
    asm("v_cvt_pk_bf16_f32 %0, %1, %2" : "=v"(r) : "v"(lo), "v"(hi));
    return r;
}

// e where mask-bit of this lane is set, else 0.0f. m is wave-uniform (SGPR pair).
__device__ __forceinline__ float sel0(float e, unsigned long long m) {
    float r;
    asm("v_cndmask_b32 %0, 0, %1, %2" : "=v"(r) : "v"(e), "s"(m));
    return r;
}

__device__ __forceinline__ void gld16(const __bf16* g, __bf16* l) {
    __builtin_amdgcn_global_load_lds((const __attribute__((address_space(1))) void*)g,
                                     (__attribute__((address_space(3))) void*)l, 16, 0, 0);
}

// ---------------- Kernel 0: mask permute (y<NB) + Wo f32->bf16 (y==NB) ----------------
// mq word (n,qg,w,g,kc,kt*4+r): bit l = (mask[n][qg*128+g*64+w*16+(l&15)][kc*64+kt*16+(l>>4)*4+r] != 0)
__global__ __launch_bounds__(256) void mask_perm(const int* __restrict__ mask,
                                                 unsigned long long* __restrict__ mq,
                                                 const float* __restrict__ Wo,
                                                 __bf16* __restrict__ Wob)
{
    __shared__ __align__(16) int Ms[128 * 68];
    const int t = threadIdx.x;
    if (blockIdx.y == NB) {
        // Wo conversion: 128 blocks x 256 thr x 32 elems = 1M elems, fully coalesced
        const size_t base = (size_t)blockIdx.x * 8192;
        #pragma unroll
        for (int jj = 0; jj < 8; ++jj) {
            const size_t off = base + (size_t)jj * 1024 + (size_t)t * 4;
            float4 f = *(const float4*)&Wo[off];
            union { __bf16 b[4]; uint2 u; } tmp;
            tmp.b[0] = (__bf16)f.x; tmp.b[1] = (__bf16)f.y;
            tmp.b[2] = (__bf16)f.z; tmp.b[3] = (__bf16)f.w;
            *(uint2*)&Wob[off] = tmp.u;
        }
        return;
    }
    const int w = t >> 6, lane = t & 63, quad = lane >> 4, lq = lane & 15;
    const int n = blockIdx.y;
    const int qg = blockIdx.x >> 4, kc = blockIdx.x & 15;
    const int* src = mask + ((size_t)n * SEQ + qg * 128) * SEQ + kc * 64;
    // 128 rows x 64 ints, 16 uint4 per row, 2048 chunks over 256 threads
    #pragma unroll
    for (int i = 0; i < 8; ++i) {
        const int c = t + i * 256, row = c >> 4, seg = c & 15;
        uint4 v = *(const uint4*)&src[(size_t)row * SEQ + seg * 4];
        *(uint4*)&Ms[row * 68 + seg * 4] = v;
    }
    __syncthreads();
    #pragma unroll
    for (int g = 0; g < 2; ++g) {
        const int row = (g * 64 + w * 16 + lq) * 68 + quad * 4;
        unsigned long long* dst = mq + ((size_t)(((n * 8 + qg) * 4 + w) * 2 + g) * 16 + kc) * 16;
        #pragma unroll
        for (int kt = 0; kt < 4; ++kt)
            #pragma unroll
            for (int r = 0; r < 4; ++r) {
                unsigned long long b = __ballot(Ms[row + kt * 16 + r] != 0);
                if (lane == 0) dst[kt * 4 + r] = b;
            }
    }
}

// ---------------- Kernel 1: per-head projection, MFMA (v1, proven) ----------------
// z=0: Q out (N,H,SEQ,64), pre-scaled by QSCALE.  z=1: K out.  z=2: V out transposed (N,H,64,SEQ).
__global__ __launch_bounds__(256, 4) void proj_mfma(
    const float* __restrict__ q_in, const float* __restrict__ k_in, const float* __restrict__ v_in,
    const float* __restrict__ Wq, const float* __restrict__ Wk, const float* __restrict__ Wv,
    __bf16* __restrict__ qp, __bf16* __restrict__ kp, __bf16* __restrict__ vpt)
{
    const int z = blockIdx.z;
    const float* X  = (z == 0) ? q_in : (z == 1) ? k_in : v_in;
    const float* Wf = (z == 0) ? Wq   : (z == 1) ? Wk   : Wv;

    __shared__ __align__(16) __bf16 Wb[64 * 72];  // Wb[e][d]
    __shared__ __align__(16) __bf16 Xb[64 * 72];  // Xb[l][d]; reused as output tile
    const int t = threadIdx.x;
    const int nh = blockIdx.y, n = nh >> 4, h = nh & 15;
    const int l0 = blockIdx.x * 64;
    for (int i = t; i < 4096; i += 256)
        Wb[(i >> 6) * 72 + (i & 63)] = (__bf16)Wf[i];
    {
        const int row = t >> 2, seg = (t & 3) * 16;
        const float* src = X + ((size_t)(n * SEQ + l0 + row)) * EMB + h * 64 + seg;
        union { __bf16 b[16]; uint4 u[2]; } tmp;
        #pragma unroll
        for (int jj = 0; jj < 4; ++jj) {
            float4 f = ((const float4*)src)[jj];
            tmp.b[jj*4+0] = (__bf16)f.x; tmp.b[jj*4+1] = (__bf16)f.y;
            tmp.b[jj*4+2] = (__bf16)f.z; tmp.b[jj*4+3] = (__bf16)f.w;
        }
        *(uint4*)&Xb[row * 72 + seg]     = tmp.u[0];
        *(uint4*)&Xb[row * 72 + seg + 8] = tmp.u[1];
    }
    __syncthreads();
    const int w = t >> 6, lane = t & 63, quad = lane >> 4, lr = lane & 15;
    bf16x8 af[2];
    #pragma unroll
    for (int ks = 0; ks < 2; ++ks)
        af[ks] = *(const bf16x8*)&Xb[(w * 16 + lr) * 72 + ks * 32 + quad * 8];
    const f32x4 zero4 = {0.f, 0.f, 0.f, 0.f};
    f32x4 acc[4];
    #pragma unroll
    for (int et = 0; et < 4; ++et) {
        acc[et] = zero4;
        #pragma unroll
        for (int ks = 0; ks < 2; ++ks) {
            bf16x8 bfrag = *(const bf16x8*)&Wb[(et * 16 + lr) * 72 + ks * 32 + quad * 8];
            acc[et] = __builtin_amdgcn_mfma_f32_16x16x32_bf16(af[ks], bfrag, acc[et], 0, 0, 0);
        }
    }
    if (z == 0) {
        #pragma unroll
        for (int et = 0; et < 4; ++et) acc[et] *= QSCALE;
    }
    __syncthreads();   // all waves past their Xb fragment reads (acc dependency)
    if (z < 2) {
        // tile[l][e] then coalesced row store
        #pragma unroll
        for (int et = 0; et < 4; ++et)
            #pragma unroll
            for (int rr = 0; rr < 4; ++rr)
                Xb[(w * 16 + quad * 4 + rr) * 72 + et * 16 + lr] = (__bf16)acc[et][rr];
        __syncthreads();
        const int row = t >> 2, seg = (t & 3) * 16;
        uint4 a = *(uint4*)&Xb[row * 72 + seg];
        uint4 b = *(uint4*)&Xb[row * 72 + seg + 8];
        __bf16* outp = (z == 0) ? qp : kp;
        __bf16* dst = outp + (size_t)nh * 65536 + (size_t)(l0 + row) * 64 + seg;
        *(uint4*)&dst[0] = a;
        *(uint4*)&dst[8] = b;
    } else {
        // tile[e][l] then coalesced row store into (N,H,64,SEQ)
        #pragma unroll
        for (int et = 0; et < 4; ++et)
            #pragma unroll
            for (int rr = 0; rr < 4; ++rr)
                Xb[(et * 16 + lr) * 72 + w * 16 + quad * 4 + rr] = (__bf16)acc[et][rr];
        __syncthreads();
        const int e = t >> 2, seg = (t & 3) * 16;
        uint4 a = *(uint4*)&Xb[e * 72 + seg];
        uint4 b = *(uint4*)&Xb[e * 72 + seg + 8];
        __bf16* dst = vpt + (size_t)nh * 65536 + (size_t)e * SEQ + l0 + seg;
        *(uint4*)&dst[0] = a;
        *(uint4*)&dst[8] = b;
    }
}

// ---------------- Kernel 2: MFMA flash attention, transposed-S, no-max softmax ----------------
// v7 (proven, 53.2 us): 128 q / block, 64-key chunks, grid 1024, 32 KB LDS, 4 blocks/CU,
// counted-vmcnt 2-phase staging: K and V issued separately; K(kc+1) stays in flight across both
// barriers of iter kc (never a vmcnt(0) drain in the steady state).
__global__ __launch_bounds__(256, 4) void attn_mfma(
    const __bf16* __restrict__ qp, const __bf16* __restrict__ kp, const __bf16* __restrict__ vpt,
    const unsigned long long* __restrict__ mq, __bf16* __restrict__ attn_out)
{
    __shared__ __align__(16) __bf16 KV[2][2][64 * 64];   // [buf][0=K,1=V^T][row*64+col], 32 KB
    const int t = threadIdx.x, w = t >> 6, lane = t & 63, quad = lane >> 4, lr = lane & 15;
    const int bid = blockIdx.x;
    const int nh = bid & 127, qg = bid >> 7;       // same head -> same XCD (stride-128 blocks)
    const int n = nh >> 4, h = nh & 15;
    const int q0 = qg * 128;
    const __bf16* Q  = qp  + (size_t)nh * 65536;
    const __bf16* K  = kp  + (size_t)nh * 65536;
    const __bf16* VT = vpt + (size_t)nh * 65536;

    // wave-uniform base for the pre-permuted mask words (shared across heads)
    const int wu = __builtin_amdgcn_readfirstlane(w);
    const unsigned long long* mq_w = mq + (size_t)((n * 8 + qg) * 4 + wu) * 512;

    int qrow[2];
    bf16x8 qf[2][2];
    #pragma unroll
    for (int g = 0; g < 2; ++g) {
        qrow[g] = q0 + g * 64 + w * 16 + lr;
        qf[g][0] = *(const bf16x8*)&Q[(size_t)qrow[g] * 64 + quad * 8];
        qf[g][1] = *(const bf16x8*)&Q[(size_t)qrow[g] * 64 + 32 + quad * 8];
    }

    // all-ones A fragment: Lacc[g] = ones(16x32) @ P^T accumulates column sums of P^T = l per q.
    bf16x8 onesf;
    #pragma unroll
    for (int i = 0; i < 8; ++i) onesf[i] = (__bf16)1.0f;

    // staging: thread t covers 16B chunks c=t and c=t+256 of each 8 KB tile.
    // source chunk index is XOR-swizzled by (row&7) so the *read* swizzle lands on linear data.
    const int srow = t >> 3, sc8 = t & 7;
    const int sswz = (sc8 ^ (srow & 7)) * 8;           // element offset of swizzled 16B chunk
    const int kofs = srow * 64 + sswz;                 // K[row][*]; second chunk = +32 rows
    const int vofs = srow * SEQ + sswz;                // V^T[d][*]; second chunk = +32 rows

    auto issueK = [&](int kc) {                        // 2 vmem instrs
        __bf16* kb = (__bf16*)&KV[kc & 1][0][0];
        const __bf16* ksrc = K + (size_t)kc * 4096 + kofs;
        gld16(ksrc,           kb + t * 8);
        gld16(ksrc + 32 * 64, kb + t * 8 + 2048);
    };
    auto issueV = [&](int kc) {                        // 2 vmem instrs
        __bf16* vb = (__bf16*)&KV[kc & 1][1][0];
        const __bf16* vsrc = VT + (size_t)kc * 64 + vofs;
        gld16(vsrc,            vb + t * 8);
        gld16(vsrc + 32 * SEQ, vb + t * 8 + 2048);
    };

    // per-lane swizzled fragment offsets: chunk j = 4*ks+quad lives at slot j^(lr&7)
    const int s0 = ((quad ^ (lr & 7))) * 8;            // ks=0
    const int s1 = s0 ^ 32;                            // ks=1 (chunk j^4 -> slot offset ^32 elems)

    const f32x4 zero4 = {0.f, 0.f, 0.f, 0.f};
    f32x4 O[2][4];
    f32x4 Lacc[2];
    #pragma unroll
    for (int g = 0; g < 2; ++g) {
        Lacc[g] = zero4;
        #pragma unroll
        for (int mt = 0; mt < 4; ++mt) O[g][mt] = zero4;
    }

    // prologue: 6 vmem in flight (K0, V0, K1)
    issueK(0); issueV(0); issueK(1);
    for (int kc = 0; kc < 16; ++kc) {
        // --- K phase: need K(kc) landed; V(kc) [+K(kc+1) if kc<15] stay in flight ---
        if (kc < 15) asm volatile("s_waitcnt vmcnt(4)" ::: "memory");
        else         asm volatile("s_waitcnt vmcnt(2)" ::: "memory");
        __builtin_amdgcn_s_barrier();
        const __bf16* Kb = (const __bf16*)&KV[kc & 1][0][0];
        const __bf16* Vb = (const __bf16*)&KV[kc & 1][1][0];

        // S^T = K @ Q^T : col = q (lr), row = key = kt*16 + quad*4 + r.  kf shared across groups.
        f32x4 S[2][4];
        __builtin_amdgcn_s_setprio(1);
        #pragma unroll
        for (int kt = 0; kt < 4; ++kt) {
            bf16x8 kf0 = *(const bf16x8*)&Kb[(kt * 16 + lr) * 64 + s0];
            bf16x8 kf1 = *(const bf16x8*)&Kb[(kt * 16 + lr) * 64 + s1];
            S[0][kt] = __builtin_amdgcn_mfma_f32_16x16x32_bf16(kf0, qf[0][0], zero4, 0, 0, 0);
            S[1][kt] = __builtin_amdgcn_mfma_f32_16x16x32_bf16(kf0, qf[1][0], zero4, 0, 0, 0);
            S[0][kt] = __builtin_amdgcn_mfma_f32_16x16x32_bf16(kf1, qf[0][1], S[0][kt], 0, 0, 0);
            S[1][kt] = __builtin_amdgcn_mfma_f32_16x16x32_bf16(kf1, qf[1][1], S[1][kt], 0, 0, 0);
        }
        __builtin_amdgcn_s_setprio(0);

        // --- V phase: need V(kc) landed; K(kc+1) stays in flight ---
        if (kc < 15) asm volatile("s_waitcnt vmcnt(2)" ::: "memory");
        else         asm volatile("s_waitcnt vmcnt(0)" ::: "memory");
        __builtin_amdgcn_s_barrier();
        if (kc + 1 < 16) issueV(kc + 1);   // safe: all waves past PV(kc-1) at this barrier

        // exp (unconditional, |S|<~3) -> one v_cndmask with SGPR lane-mask -> P^T B-fragments.
        bf16x8 pf[2][2];
        #pragma unroll
        for (int g = 0; g < 2; ++g) {
            const unsigned long long* Mg = mq_w + g * 256 + kc * 16;
            float ev[16];
            #pragma unroll
            for (int kt = 0; kt < 4; ++kt)
                #pragma unroll
                for (int r = 0; r < 4; ++r)
                    ev[kt * 4 + r] = sel0(EXPD(S[g][kt][r]), Mg[kt * 4 + r]);
            // lane(quad,lr) holds P^T keys 16kt+4quad+{0..3}; B-frag needs keys 32ks+8quad+{0..7}.
            #pragma unroll
            for (int ks = 0; ks < 2; ++ks) {
                const int ka = (2 * ks) * 4, kb2 = (2 * ks + 1) * 4;
                int d0 = cvtpk_bf16(ev[ka + 0], ev[ka + 1]);
                int d1 = cvtpk_bf16(ev[ka + 2], ev[ka + 3]);
                int d2 = cvtpk_bf16(ev[kb2 + 0], ev[kb2 + 1]);
                int d3 = cvtpk_bf16(ev[kb2 + 2], ev[kb2 + 3]);
                asm("v_permlane32_swap_b32 %0, %1" : "+v"(d0), "+v"(d2));
                asm("v_permlane16_swap_b32 %0, %1" : "+v"(d0), "+v"(d2));
                asm("v_permlane32_swap_b32 %0, %1" : "+v"(d1), "+v"(d3));
                asm("v_permlane16_swap_b32 %0, %1" : "+v"(d1), "+v"(d3));
                union { int di[4]; bf16x8 v; } pb;
                pb.di[0] = d0; pb.di[1] = d1; pb.di[2] = d2; pb.di[3] = d3;
                pf[g][ks] = pb.v;
            }
        }

        // O^T += V^T @ P^T ; V-frags shared across the two q-groups; l via ones-MFMA.
        __builtin_amdgcn_s_setprio(1);
        #pragma unroll
        for (int ks = 0; ks < 2; ++ks) {
            const int sv = ks ? s1 : s0;
            Lacc[0] = __builtin_amdgcn_mfma_f32_16x16x32_bf16(onesf, pf[0][ks], Lacc[0], 0, 0, 0);
            Lacc[1] = __builtin_amdgcn_mfma_f32_16x16x32_bf16(onesf, pf[1][ks], Lacc[1], 0, 0, 0);
            #pragma unroll
            for (int mt = 0; mt < 4; ++mt) {
                bf16x8 vf = *(const bf16x8*)&Vb[(mt * 16 + lr) * 64 + sv];
                O[0][mt] = __builtin_amdgcn_mfma_f32_16x16x32_bf16(vf, pf[0][ks], O[0][mt], 0, 0, 0);
                O[1][mt] = __builtin_amdgcn_mfma_f32_16x16x32_bf16(vf, pf[1][ks], O[1][mt], 0, 0, 0);
            }
        }
        __builtin_amdgcn_s_setprio(0);
        if (kc + 2 < 16) issueK(kc + 2);   // safe: all waves finished QK(kc) reads at barrierV
    }
    #pragma unroll
    for (int g = 0; g < 2; ++g) {
        // every row of the ones-MFMA result equals the column sum: l for q=lr is in Lacc[g][*].
        const float linv = 1.0f / Lacc[g][0];
        #pragma unroll
        for (int mt = 0; mt < 4; ++mt) {
            union { __bf16 b[4]; uint2 u; } pk;
            #pragma unroll
            for (int r = 0; r < 4; ++r) pk.b[r] = (__bf16)(O[g][mt][r] * linv);
            *(uint2*)&attn_out[((size_t)n * SEQ + qrow[g]) * EMB + h * 64 + mt * 16 + quad * 4] = pk.u;
        }
    }
}

// ---------------- Kernel 3: out = A(8192x1024) @ Wob^T + bo, MFMA ----------------
// v4: 128x128 tile (m97 shape), BK=32, 4 waves x 64x64 acc[4][4] -> MFMA:ds_read = 2:1
// (was 16:12, LDS-read-bound at ~15 us/CU; now ~10). Double-buffered 32 KB LDS, gld16
// staging with mod-4 source swizzle slot^=(row>>1)&3 -> all fragment reads 2-way max (free).
// XCD band swizzle for grid (8,64): XCD s owns 8 contiguous A row-bands (2 MB) + Wob (2 MB).
__global__ __launch_bounds__(256, 3) void out_gemm_mfma(
    const __bf16* __restrict__ A, const __bf16* __restrict__ B,
    const float* __restrict__ bo, float* __restrict__ out)
{
    __shared__ __align__(16) __bf16 AB[2][2 * 128 * 32];   // [buf][A 4096 | B 4096] elems, 32 KB
    const int t = threadIdx.x, w = t >> 6, lane = t & 63, quad = lane >> 4, lr = lane & 15;
    const int wr = (w >> 1) * 64, wc = (w & 1) * 64;
    // band swizzle: L = bx + 8*by in [0,512); XCD s = L&7 gets by' in [8s, 8s+8)
    const int L = blockIdx.x + 8 * blockIdx.y;
    const int s = L & 7, c = L >> 3;
    const int bx = c >> 3, by = (s << 3) | (c & 7);
    const int r0 = by * 128, e0 = bx * 128;

    // staging: chunk c = t covers (row t>>2, slot t&3); source slot XOR-swizzled by (row>>1)&3.
    // rows row and row+64 share the same swizzle ((64>>1)&3 == 0), so one offset serves both.
    const int srow = t >> 2;
    const int sslot = ((t & 3) ^ ((t >> 3) & 3)) * 8;

    auto issue = [&](int st) {
        __bf16* buf = (__bf16*)&AB[st & 1][0];
        const __bf16* as = A + (size_t)(r0 + srow) * EMB + st * 32 + sslot;
        const __bf16* bs = B + (size_t)(e0 + srow) * EMB + st * 32 + sslot;
        gld16(as,            buf + t * 8);
        gld16(as + 64 * EMB, buf + 2048 + t * 8);
        gld16(bs,            buf + 4096 + t * 8);
        gld16(bs + 64 * EMB, buf + 6144 + t * 8);
    };

    // fragment read offset: slot quad of row lives at slot quad^((row>>1)&3); wr/wc/mt*16 are
    // all ≡0 mod 8 rows, so the swizzle term depends only on lr.
    const int sw = (quad ^ ((lr >> 1) & 3)) * 8;
    const f32x4 zero4 = {0.f, 0.f, 0.f, 0.f};
    f32x4 acc[4][4];
    #pragma unroll
    for (int mt = 0; mt < 4; ++mt)
        #pragma unroll
        for (int nt = 0; nt < 4; ++nt) acc[mt][nt] = zero4;

    issue(0);
    for (int st = 0; st < 32; ++st) {
        __syncthreads();                   // vmcnt drained before barrier: tile st in LDS
        if (st + 1 < 32) issue(st + 1);
        const __bf16* buf = (const __bf16*)&AB[st & 1][0];
        bf16x8 af[4], bf[4];
        #pragma unroll
        for (int mt = 0; mt < 4; ++mt)
            af[mt] = *(const bf16x8*)&buf[(wr + mt * 16 + lr) * 32 + sw];
        #pragma unroll
        for (int nt = 0; nt < 4; ++nt)
            bf[nt] = *(const bf16x8*)&buf[4096 + (wc + nt * 16 + lr) * 32 + sw];
        __builtin_amdgcn_s_setprio(1);
        #pragma unroll
        for (int mt = 0; mt < 4; ++mt)
            #pragma unroll
            for (int nt = 0; nt < 4; ++nt)
                acc[mt][nt] = __builtin_amdgcn_mfma_f32_16x16x32_bf16(af[mt], bf[nt], acc[mt][nt], 0, 0, 0);
        __builtin_amdgcn_s_setprio(0);
    }
    float bv[4];
    #pragma unroll
    for (int nt = 0; nt < 4; ++nt) bv[nt] = bo[e0 + wc + nt * 16 + lr];
    #pragma unroll
    for (int mt = 0; mt < 4; ++mt)
        #pragma unroll
        for (int nt = 0; nt < 4; ++nt)
            #pragma unroll
            for (int rr = 0; rr < 4; ++rr)
                out[(size_t)(r0 + wr + mt * 16 + quad * 4 + rr) * EMB + e0 + wc + nt * 16 + lr] =
                    acc[mt][nt][rr] + bv[nt];
}

extern "C" void kernel_launch(void* const* d_in, const int* in_sizes, int n_in,
                              void* d_out, int out_size, void* d_ws, size_t ws_size,
                              hipStream_t stream) {
    const float* values = (const float*)d_in[0];
    const float* keys   = (const float*)d_in[1];
    const float* query  = (const float*)d_in[2];
    const int*   mask   = (const int*)d_in[3];
    const float* Wv     = (const float*)d_in[4];
    const float* Wk     = (const float*)d_in[5];
    const float* Wq     = (const float*)d_in[6];
    const float* Wo     = (const float*)d_in[7];
    const float* bo     = (const float*)d_in[8];
    float* out = (float*)d_out;

    const size_t per = (size_t)NB * HEADS * SEQ * HD;  // 8,388,608 elems
    __bf16* qp   = (__bf16*)d_ws;
    __bf16* kp   = qp + per;
    __bf16* vpt  = kp + per;                         // V transposed (N,H,64,SEQ)
    __bf16* attn = vpt + per;                        // (N*SEQ, EMB)
    __bf16* Wob  = attn + (size_t)NB * SEQ * EMB;
    unsigned long long* maskq = (unsigned long long*)(Wob + (size_t)EMB * EMB);  // 1 MB

    mask_perm<<<dim3(128, NB + 1), 256, 0, stream>>>(mask, maskq, Wo, Wob);
    proj_mfma<<<dim3(16, 128, 3), 256, 0, stream>>>(query, keys, values, Wq, Wk, Wv, qp, kp, vpt);
    attn_mfma<<<1024, 256, 0, stream>>>(qp, kp, vpt, maskq, attn);
    out_gemm_mfma<<<dim3(8, 64), 256, 0, stream>>>(attn, Wob, bo, out);
}